// Round 21
// baseline (392.597 us; speedup 1.0000x reference)
//
#include <hip/hip_runtime.h>
#include <math.h>

#define CDIV(a,b) (((a)+(b)-1)/(b))
typedef unsigned int u32;

__device__ __forceinline__ float sigmoidf_(float x) { return 1.f / (1.f + __expf(-x)); }

template<int N>
__device__ __forceinline__ void ldsv(float* d, const float* s) {
    #pragma unroll
    for (int q = 0; q < N / 4; ++q) {
        float4 w4 = *reinterpret_cast<const float4*>(s + q * 4);
        d[q*4] = w4.x; d[q*4+1] = w4.y; d[q*4+2] = w4.z; d[q*4+3] = w4.w;
    }
}

// ---------------- mask dtype detection ----------------
__global__ void k_detect(const u32* __restrict__ w, int n, u32* __restrict__ flag) {
    u32 local = 0;
    for (int i = blockIdx.x * blockDim.x + threadIdx.x; i < n; i += gridDim.x * blockDim.x) {
        u32 v = w[i];
        if (v == 0x3F800000u) local |= 2u;
        else if (v > 1u)      local |= 1u;
    }
    if (local) atomicOr(flag, local);
}

__global__ void k_expand(const void* __restrict__ mraw, const u32* __restrict__ flag,
                         float* __restrict__ m, int n) {
    int i = blockIdx.x * blockDim.x + threadIdx.x;
    if (i >= n) return;
    u32 f = *flag;
    float v;
    if (f & 2u)      v = ((const float*)mraw)[i];
    else if (f & 1u) v = ((const unsigned char*)mraw)[i] ? 1.f : 0.f;
    else             v = ((const int*)mraw)[i] ? 1.f : 0.f;
    m[i] = v;
}

// ---------------- mask max-pool 2x2x2 + count ----------------
__global__ void k_pool(const float* __restrict__ mi, float* __restrict__ mo,
                       float* __restrict__ cnt, int Si, int n) {
    int So = Si >> 1;
    int i = blockIdx.x * blockDim.x + threadIdx.x;
    float v = 0.f;
    if (i < n) {
        int x = i % So; int t = i / So;
        int y = t % So; t /= So;
        int z = t % So; int b = t / So;
        const float* p = mi + (size_t)b * Si * Si * Si;
        #pragma unroll
        for (int dz = 0; dz < 2; dz++)
        #pragma unroll
        for (int dy = 0; dy < 2; dy++)
        #pragma unroll
        for (int dx = 0; dx < 2; dx++) {
            float q = p[((size_t)(2 * z + dz) * Si + (2 * y + dy)) * Si + (2 * x + dx)];
            v = fmaxf(v, q);
        }
        mo[i] = v;
    }
    __shared__ float red[256];
    red[threadIdx.x] = v; __syncthreads();
    for (int s = 128; s > 0; s >>= 1) {
        if (threadIdx.x < s) red[threadIdx.x] += red[threadIdx.x + s];
        __syncthreads();
    }
    if (threadIdx.x == 0) atomicAdd(cnt, red[0]);
}

// ============ conv1: NCDHW feats(3ch)+mask -> CL e0, 1 voxel/thread ===========
__global__ __launch_bounds__(256)
void k_conv1(const float* __restrict__ feats, const float* __restrict__ m0,
             const float* __restrict__ W, float* __restrict__ out,
             const float* __restrict__ m1, float* __restrict__ stats) {
    constexpr int SIN = 96;
    constexpr int V0 = SIN * SIN * SIN, V1 = 48 * 48 * 48;
    __shared__ __align__(16) float wlds[27 * 3 * 16];
    __shared__ float sred[4][32];
    for (int idx = threadIdx.x; idx < 27 * 3 * 16; idx += 256) wlds[idx] = W[idx];
    __syncthreads();
    int chunk = blockIdx.x * 256 + threadIdx.x;   // exact: 864*256 = 2*V1
    int b = chunk / V1; int s = chunk - b * V1;
    int x = s % 48, y = (s / 48) % 48, z = s / 2304;
    float acc[16];
    #pragma unroll
    for (int co = 0; co < 16; ++co) acc[co] = 0.f;
    const float* bi = feats + (size_t)b * 3 * V0;
    const float* bm = m0 + (size_t)b * V0;
    #pragma unroll
    for (int kz = 0; kz < 3; ++kz) {
        int iz = 2 * z - 1 + kz; if (iz < 0) continue;
        #pragma unroll
        for (int ky = 0; ky < 3; ++ky) {
            int iy = 2 * y - 1 + ky; if (iy < 0) continue;
            #pragma unroll
            for (int kx = 0; kx < 3; ++kx) {
                int ix = 2 * x - 1 + kx; if (ix < 0) continue;
                int off = (iz * SIN + iy) * SIN + ix;
                float mv = bm[off];
                if (mv != 0.f) {
                    float f0 = bi[off], f1 = bi[V0 + off], f2 = bi[2 * V0 + off];
                    const float* wp = &wlds[((kz * 3 + ky) * 3 + kx) * 48];
                    #pragma unroll
                    for (int co = 0; co < 16; ++co)
                        acc[co] += f0 * wp[co] + f1 * wp[16 + co] + f2 * wp[32 + co];
                }
            }
        }
    }
    float mm = m1[chunk];
    #pragma unroll
    for (int co = 0; co < 16; ++co) acc[co] *= mm;
    float* op = out + (size_t)chunk * 16;
    #pragma unroll
    for (int q = 0; q < 4; ++q)
        *reinterpret_cast<float4*>(op + q * 4) =
            make_float4(acc[q*4], acc[q*4+1], acc[q*4+2], acc[q*4+3]);
    float s1[16], s2[16];
    #pragma unroll
    for (int co = 0; co < 16; ++co) { s1[co] = acc[co]; s2[co] = acc[co] * acc[co]; }
    #pragma unroll
    for (int co = 0; co < 16; ++co)
        for (int off = 1; off < 64; off <<= 1) {
            s1[co] += __shfl_xor(s1[co], off);
            s2[co] += __shfl_xor(s2[co], off);
        }
    int lane = threadIdx.x & 63, wid = threadIdx.x >> 6;
    if (lane == 0) {
        #pragma unroll
        for (int co = 0; co < 16; ++co) { sred[wid][co] = s1[co]; sred[wid][16 + co] = s2[co]; }
    }
    __syncthreads();
    if (threadIdx.x < 32) {
        int t = threadIdx.x;
        float v = sred[0][t] + sred[1][t] + sred[2][t] + sred[3][t];
        int addr = (t < 16) ? t : (128 + t - 16);
        atomicAdd(&stats[addr], v);
    }
}

// ============ channels-last strided conv 3x3x3 s2 p1, gated output ============
template<int CI, int CO, int CO_T, int SIN, int SOUT, bool STATS>
__global__ __launch_bounds__(256)
void k_convCL(const float* __restrict__ in, const float* __restrict__ W,
              float* __restrict__ out, const float* __restrict__ mout,
              float* __restrict__ stats) {
    constexpr int SIN3 = SIN * SIN * SIN, SOUT3 = SOUT * SOUT * SOUT;
    constexpr int NW = 27 * CI * CO_T;
    __shared__ __align__(16) float wlds[NW];
    __shared__ float sred[STATS ? 4 : 1][2 * CO_T];
    const int cobase = blockIdx.y * CO_T;
    for (int idx = threadIdx.x; idx < NW; idx += 256) {
        int t = idx / (CI * CO_T);
        int rem = idx - t * CI * CO_T;
        int ci = rem / CO_T, co = rem - ci * CO_T;
        wlds[idx] = W[(size_t)(t * CI + ci) * CO + cobase + co];
    }
    __syncthreads();
    int chunk = blockIdx.x * 256 + threadIdx.x;
    bool active = chunk < 2 * SOUT3;
    if (!STATS && !active) return;
    float acc[CO_T];
    #pragma unroll
    for (int co = 0; co < CO_T; ++co) acc[co] = 0.f;
    if (active) {
        int b = chunk / SOUT3, s = chunk - b * SOUT3;
        int x = s % SOUT, y = (s / SOUT) % SOUT, z = s / (SOUT * SOUT);
        const float* bi = in + (size_t)b * SIN3 * CI;
        #pragma unroll
        for (int kz = 0; kz < 3; ++kz) {
            int iz = 2 * z - 1 + kz; if (iz < 0 || iz >= SIN) continue;
            #pragma unroll
            for (int ky = 0; ky < 3; ++ky) {
                int iy = 2 * y - 1 + ky; if (iy < 0 || iy >= SIN) continue;
                #pragma unroll
                for (int kx = 0; kx < 3; ++kx) {
                    int ix = 2 * x - 1 + kx; if (ix < 0 || ix >= SIN) continue;
                    const float* p = bi + (size_t)((iz * SIN + iy) * SIN + ix) * CI;
                    const float* wp = &wlds[((kz * 3 + ky) * 3 + kx) * CI * CO_T];
                    #pragma unroll
                    for (int cq = 0; cq < CI / 4; ++cq) {
                        float4 v = *reinterpret_cast<const float4*>(p + cq * 4);
                        const float* wq = wp + cq * 4 * CO_T;
                        float vv[4] = {v.x, v.y, v.z, v.w};
                        #pragma unroll
                        for (int jj = 0; jj < 4; ++jj) {
                            float wv[CO_T];
                            ldsv<CO_T>(wv, wq + jj * CO_T);
                            #pragma unroll
                            for (int co = 0; co < CO_T; ++co)
                                acc[co] += vv[jj] * wv[co];
                        }
                    }
                }
            }
        }
        float mm = mout[chunk];
        #pragma unroll
        for (int co = 0; co < CO_T; ++co) acc[co] *= mm;
        float* op = out + (size_t)chunk * CO + cobase;
        #pragma unroll
        for (int q = 0; q < CO_T / 4; ++q)
            *reinterpret_cast<float4*>(op + q * 4) =
                make_float4(acc[q*4], acc[q*4+1], acc[q*4+2], acc[q*4+3]);
    }
    if constexpr (STATS) {
        float s1[CO_T], s2[CO_T];
        #pragma unroll
        for (int co = 0; co < CO_T; ++co) { s1[co] = acc[co]; s2[co] = acc[co] * acc[co]; }
        #pragma unroll
        for (int co = 0; co < CO_T; ++co)
            for (int off = 1; off < 64; off <<= 1) {
                s1[co] += __shfl_xor(s1[co], off);
                s2[co] += __shfl_xor(s2[co], off);
            }
        int lane = threadIdx.x & 63, wid = threadIdx.x >> 6;
        if (lane == 0) {
            #pragma unroll
            for (int co = 0; co < CO_T; ++co) { sred[wid][co] = s1[co]; sred[wid][CO_T + co] = s2[co]; }
        }
        __syncthreads();
        if (threadIdx.x < 2 * CO_T) {
            int t = threadIdx.x;
            float v = sred[0][t] + sred[1][t] + sred[2][t] + sred[3][t];
            int addr = (t < CO_T) ? (cobase + t) : (128 + cobase + t - CO_T);
            atomicAdd(&stats[addr], v);
        }
    }
}

// ============ DIRECT strided conv s2 p1, thread=(vox,co), no weight LDS =======
template<int CI, int CO, int SIN, int SOUT>
__global__ __launch_bounds__(256)
void k_convD(const float* __restrict__ in, const float* __restrict__ W,
             float* __restrict__ out, const float* __restrict__ mout,
             float* __restrict__ stats) {
    constexpr int SIN3 = SIN * SIN * SIN, SOUT3 = SOUT * SOUT * SOUT;
    int idx = blockIdx.x * 256 + threadIdx.x;
    int co = idx & (CO - 1);
    int vo = idx / CO;
    int b = vo / SOUT3; int s = vo - b * SOUT3;
    int x = s % SOUT, y = (s / SOUT) % SOUT, z = s / (SOUT * SOUT);
    const float* bi = in + (size_t)b * SIN3 * CI;
    float acc = 0.f;
    #pragma unroll 1
    for (int kz = 0; kz < 3; ++kz) {
        int iz = 2 * z - 1 + kz; if (iz < 0 || iz >= SIN) continue;
        #pragma unroll 1
        for (int ky = 0; ky < 3; ++ky) {
            int iy = 2 * y - 1 + ky; if (iy < 0 || iy >= SIN) continue;
            #pragma unroll 1
            for (int kx = 0; kx < 3; ++kx) {
                int ix = 2 * x - 1 + kx; if (ix < 0 || ix >= SIN) continue;
                const float* p = bi + (size_t)((iz * SIN + iy) * SIN + ix) * CI;
                const float* wr = W + (size_t)((kz * 3 + ky) * 3 + kx) * CI * CO + co;
                #pragma unroll 4
                for (int cq = 0; cq < CI / 4; ++cq) {
                    float4 v = *reinterpret_cast<const float4*>(p + 4 * cq);
                    acc += v.x * wr[(size_t)(4 * cq) * CO] + v.y * wr[(size_t)(4 * cq + 1) * CO]
                         + v.z * wr[(size_t)(4 * cq + 2) * CO] + v.w * wr[(size_t)(4 * cq + 3) * CO];
                }
            }
        }
    }
    float gacc = acc * mout[vo];
    out[(size_t)vo * CO + co] = gacc;
    __shared__ float sm1[256], sm2[256];
    int tid = threadIdx.x;
    sm1[tid] = gacc; sm2[tid] = gacc * gacc;
    __syncthreads();
    for (int st = 128; st >= CO; st >>= 1) {
        if (tid < st) { sm1[tid] += sm1[tid + st]; sm2[tid] += sm2[tid + st]; }
        __syncthreads();
    }
    if (tid < CO) {
        atomicAdd(&stats[tid], sm1[tid]);
        atomicAdd(&stats[128 + tid], sm2[tid]);
    }
}

// ============ DIRECT gather deconv s2, thread=(vox,co), no weight LDS =========
template<int CI, int CO, int SIN>
__global__ __launch_bounds__(256)
void k_deconvD(const float* __restrict__ in, const float* __restrict__ W,
               const float* __restrict__ mout, float* __restrict__ out,
               float* __restrict__ stats) {
    constexpr int SOUT = 2 * SIN;
    constexpr int SIN3 = SIN * SIN * SIN, SOUT3 = SOUT * SOUT * SOUT;
    int idx = blockIdx.x * 256 + threadIdx.x;
    int co = idx & (CO - 1);
    int vo = idx / CO;
    int b = vo / SOUT3; int s = vo - b * SOUT3;
    int x = s % SOUT, y = (s / SOUT) % SOUT, z = s / (SOUT * SOUT);
    int z0 = z >> 1, y0 = y >> 1, x0 = x >> 1;
    int nz = ((z & 1) && (z0 + 1 < SIN)) ? 2 : 1;
    int ny = ((y & 1) && (y0 + 1 < SIN)) ? 2 : 1;
    int nx = ((x & 1) && (x0 + 1 < SIN)) ? 2 : 1;
    int wz0 = (z & 1) ? 2 : 1, wy0 = (y & 1) ? 2 : 1, wx0 = (x & 1) ? 2 : 1;
    const float* bi = in + (size_t)b * SIN3 * CI;
    float acc = 0.f;
    #pragma unroll 1
    for (int tz = 0; tz < nz; ++tz) {
        int iz = z0 + tz, wz = tz ? 0 : wz0;
        #pragma unroll 1
        for (int ty = 0; ty < ny; ++ty) {
            int iy = y0 + ty, wy = ty ? 0 : wy0;
            #pragma unroll 1
            for (int tx = 0; tx < nx; ++tx) {
                int ix = x0 + tx, wx = tx ? 0 : wx0;
                const float* p = bi + (size_t)((iz * SIN + iy) * SIN + ix) * CI;
                const float* wr = W + (size_t)((wz * 3 + wy) * 3 + wx) * CI * CO + co;
                #pragma unroll 4
                for (int cq = 0; cq < CI / 4; ++cq) {
                    float4 v = *reinterpret_cast<const float4*>(p + 4 * cq);
                    acc += v.x * wr[(size_t)(4 * cq) * CO] + v.y * wr[(size_t)(4 * cq + 1) * CO]
                         + v.z * wr[(size_t)(4 * cq + 2) * CO] + v.w * wr[(size_t)(4 * cq + 3) * CO];
                }
            }
        }
    }
    float gacc = acc * mout[vo];
    out[(size_t)vo * CO + co] = gacc;
    __shared__ float sm1[256], sm2[256];
    int tid = threadIdx.x;
    sm1[tid] = gacc; sm2[tid] = gacc * gacc;
    __syncthreads();
    for (int st = 128; st >= CO; st >>= 1) {
        if (tid < st) { sm1[tid] += sm1[tid + st]; sm2[tid] += sm2[tid + st]; }
        __syncthreads();
    }
    if (tid < CO) {
        atomicAdd(&stats[tid], sm1[tid]);
        atomicAdd(&stats[128 + tid], sm2[tid]);
    }
}

// ============ amortized GATHER deconv s2, CL: SP_T same-parity x per thread ====
// Index: g . yh . zh . b . py . pz  (+ x-parity p slowest) -> parity-uniform waves
template<int CI, int CO, int CO_T, int SP_T, int SIN, bool STATS>
__global__ __launch_bounds__(256)
void k_deconvA(const float* __restrict__ in, const float* __restrict__ W,
               const float* __restrict__ mout, float* __restrict__ out,
               float* __restrict__ stats) {
    constexpr int SOUT = 2 * SIN;
    constexpr int SIN3 = SIN * SIN * SIN, SOUT3 = SOUT * SOUT * SOUT;
    constexpr int GX = SIN / SP_T;
    constexpr int SH = SOUT / 2;
    constexpr int HALF = 2 * SOUT * SOUT * GX;
    constexpr int NTH = 2 * HALF;
    constexpr int WST = CI * CO_T + 4;   // tap padding: 4 banks shift per tap
    __shared__ __align__(16) float wlds[27 * WST];
    __shared__ float sred[STATS ? 4 : 1][2 * CO_T];
    const int cobase = blockIdx.y * CO_T;
    for (int idx = threadIdx.x; idx < 27 * CI * CO_T; idx += 256) {
        int w = idx / (CI * CO_T);
        int rem = idx - w * (CI * CO_T);
        int ci = rem / CO_T, co = rem - ci * CO_T;
        wlds[w * WST + ci * CO_T + co] = W[(size_t)(w * CI + ci) * CO + cobase + co];
    }
    __syncthreads();
    int chunk = blockIdx.x * 256 + threadIdx.x;
    bool active = chunk < NTH;
    float acc[SP_T][CO_T];
    #pragma unroll
    for (int j = 0; j < SP_T; ++j)
    #pragma unroll
    for (int co = 0; co < CO_T; ++co) acc[j][co] = 0.f;
    int p = 0, g = 0, y = 0, z = 0, b = 0;
    if (active) {
        p = (chunk >= HALF) ? 1 : 0;
        int r = chunk - p * HALF;
        // parities in the highest bits (wave-uniform tap loops)
        g = r % GX; int q = r / GX;
        int yh = q % SH; q /= SH;
        int zh = q % SH; q /= SH;
        b = q % 2; q /= 2;
        int py = q % 2;
        int pz = q / 2;
        y = 2 * yh + py; z = 2 * zh + pz;
        int x0 = SP_T * g;
        int z0 = zh, y0 = yh;
        int nz = (pz && (z0 + 1 < SIN)) ? 2 : 1;
        int ny = (py && (y0 + 1 < SIN)) ? 2 : 1;
        int wz0 = pz ? 2 : 1, wy0 = py ? 2 : 1;
        bool lastok = (x0 + SP_T < SIN);
        const float* bi = in + (size_t)b * SIN3 * CI;
        #pragma unroll 1
        for (int tz = 0; tz < nz; ++tz) {
            int iz = z0 + tz, wz = tz ? 0 : wz0;
            #pragma unroll 1
            for (int ty = 0; ty < ny; ++ty) {
                int iy = y0 + ty, wy = ty ? 0 : wy0;
                const float* rp = bi + (size_t)((iz * SIN + iy) * SIN + x0) * CI;
                #pragma unroll 2
                for (int cq = 0; cq < CI / 4; ++cq) {
                    float v[SP_T + 1][4];
                    #pragma unroll
                    for (int t = 0; t < SP_T; ++t) {
                        float4 q4 = *reinterpret_cast<const float4*>(rp + (size_t)t * CI + cq * 4);
                        v[t][0] = q4.x; v[t][1] = q4.y; v[t][2] = q4.z; v[t][3] = q4.w;
                    }
                    if (p) {
                        float4 q4 = make_float4(0.f, 0.f, 0.f, 0.f);
                        if (lastok)
                            q4 = *reinterpret_cast<const float4*>(rp + (size_t)SP_T * CI + cq * 4);
                        v[SP_T][0] = q4.x; v[SP_T][1] = q4.y; v[SP_T][2] = q4.z; v[SP_T][3] = q4.w;
                    }
                    if (p == 0) {
                        const float* wb = &wlds[((wz * 3 + wy) * 3 + 1) * WST + cq * 4 * CO_T];
                        #pragma unroll
                        for (int jj = 0; jj < 4; ++jj) {
                            float wv[CO_T];
                            ldsv<CO_T>(wv, wb + jj * CO_T);
                            #pragma unroll
                            for (int j = 0; j < SP_T; ++j) {
                                float iv = v[j][jj];
                                #pragma unroll
                                for (int co = 0; co < CO_T; ++co) acc[j][co] += iv * wv[co];
                            }
                        }
                    } else {
                        const float* wb2 = &wlds[((wz * 3 + wy) * 3 + 2) * WST + cq * 4 * CO_T];
                        const float* wb0 = &wlds[((wz * 3 + wy) * 3 + 0) * WST + cq * 4 * CO_T];
                        #pragma unroll
                        for (int jj = 0; jj < 4; ++jj) {
                            float wv2[CO_T], wv0[CO_T];
                            ldsv<CO_T>(wv2, wb2 + jj * CO_T);
                            ldsv<CO_T>(wv0, wb0 + jj * CO_T);
                            #pragma unroll
                            for (int j = 0; j < SP_T; ++j) {
                                float ivA = v[j][jj], ivB = v[j + 1][jj];
                                #pragma unroll
                                for (int co = 0; co < CO_T; ++co)
                                    acc[j][co] += ivA * wv2[co] + ivB * wv0[co];
                            }
                        }
                    }
                }
            }
        }
        int sp = b * SOUT3 + (z * SOUT + y) * SOUT;
        int x0o = 2 * SP_T * g + p;
        #pragma unroll
        for (int j = 0; j < SP_T; ++j) {
            int vox = sp + x0o + 2 * j;
            float mm = mout[vox];
            #pragma unroll
            for (int co = 0; co < CO_T; ++co) acc[j][co] *= mm;
            float* op = out + (size_t)vox * CO + cobase;
            #pragma unroll
            for (int q4 = 0; q4 < CO_T / 4; ++q4)
                *reinterpret_cast<float4*>(op + q4 * 4) =
                    make_float4(acc[j][q4*4], acc[j][q4*4+1], acc[j][q4*4+2], acc[j][q4*4+3]);
        }
    }
    if constexpr (STATS) {
        float s1[CO_T], s2[CO_T];
        #pragma unroll
        for (int co = 0; co < CO_T; ++co) {
            float a = 0.f, b2 = 0.f;
            #pragma unroll
            for (int j = 0; j < SP_T; ++j) { a += acc[j][co]; b2 += acc[j][co] * acc[j][co]; }
            s1[co] = a; s2[co] = b2;
        }
        #pragma unroll
        for (int co = 0; co < CO_T; ++co)
            for (int off = 1; off < 64; off <<= 1) {
                s1[co] += __shfl_xor(s1[co], off);
                s2[co] += __shfl_xor(s2[co], off);
            }
        int lane = threadIdx.x & 63, wid = threadIdx.x >> 6;
        if (lane == 0) {
            #pragma unroll
            for (int co = 0; co < CO_T; ++co) { sred[wid][co] = s1[co]; sred[wid][CO_T + co] = s2[co]; }
        }
        __syncthreads();
        if (threadIdx.x < 2 * CO_T) {
            int t = threadIdx.x;
            float v = sred[0][t] + sred[1][t] + sred[2][t] + sred[3][t];
            int addr = (t < CO_T) ? (cobase + t) : (128 + cobase + t - CO_T);
            atomicAdd(&stats[addr], v);
        }
    }
}

// ============ final deconv GATHER X4, parity-uniform waves ====================
__global__ __launch_bounds__(256)
void k_deconv_final(const float* __restrict__ in, const float* __restrict__ W,
                    const float* __restrict__ m0, float* __restrict__ out,
                    const float* __restrict__ ow, const float* __restrict__ ob,
                    float* __restrict__ p1out) {
    constexpr int SI = 48, SO = 96;
    constexpr int SI3 = SI * SI * SI, SO3 = SO * SO * SO;
    constexpr int WST = 68;   // 64 + 4 pad
    __shared__ __align__(16) float wlds[27 * WST];
    for (int idx = threadIdx.x; idx < 27 * 64; idx += 256) {
        int w = idx >> 6; int rem = idx & 63;
        int ci = rem >> 2, co = rem & 3;
        wlds[w * WST + ci * 4 + co] = (co < 3) ? W[(size_t)(w * 16 + ci) * 3 + co] : 0.f;
    }
    __syncthreads();
    int t = blockIdx.x * 256 + threadIdx.x;     // exact 1728*256 = 442368
    int x4 = t % 24; int r = t / 24;
    int yh = r % 48; r /= 48;
    int zh = r % 48; r /= 48;
    int b  = r % 2;  r /= 2;
    int py = r % 2;
    int pz = r / 2;
    int y = 2 * yh + py, z = 2 * zh + pz;
    int x0 = x4 * 4, kxb = x4 * 2;
    int izs[2], wzs[2], nz = 1;
    if (pz) { izs[0] = zh; wzs[0] = 2;
              if (zh + 1 < SI) { izs[1] = zh + 1; wzs[1] = 0; nz = 2; } }
    else    { izs[0] = zh; wzs[0] = 1; }
    int iys[2], wys[2], ny = 1;
    if (py) { iys[0] = yh; wys[0] = 2;
              if (yh + 1 < SI) { iys[1] = yh + 1; wys[1] = 0; ny = 2; } }
    else    { iys[0] = yh; wys[0] = 1; }
    bool has2 = (kxb + 2 < SI);
    float acc[4][3];
    #pragma unroll
    for (int o = 0; o < 4; ++o)
    #pragma unroll
    for (int c = 0; c < 3; ++c) acc[o][c] = 0.f;
    const float* bi = in + (size_t)b * SI3 * 16;
    #pragma unroll 1
    for (int tz = 0; tz < nz; ++tz)
    #pragma unroll 1
    for (int ty = 0; ty < ny; ++ty) {
        const float* vp = bi + ((size_t)(izs[tz] * SI + iys[ty]) * SI + kxb) * 16;
        float v[3][16];
        #pragma unroll
        for (int q = 0; q < 4; ++q) {
            float4 a = *reinterpret_cast<const float4*>(vp + q * 4);
            float4 bq = *reinterpret_cast<const float4*>(vp + 16 + q * 4);
            v[0][q*4] = a.x; v[0][q*4+1] = a.y; v[0][q*4+2] = a.z; v[0][q*4+3] = a.w;
            v[1][q*4] = bq.x; v[1][q*4+1] = bq.y; v[1][q*4+2] = bq.z; v[1][q*4+3] = bq.w;
            float4 cq = has2 ? *reinterpret_cast<const float4*>(vp + 32 + q * 4)
                             : make_float4(0.f, 0.f, 0.f, 0.f);
            v[2][q*4] = cq.x; v[2][q*4+1] = cq.y; v[2][q*4+2] = cq.z; v[2][q*4+3] = cq.w;
        }
        const float* wb = &wlds[((wzs[tz] * 3 + wys[ty]) * 3) * WST];
        #pragma unroll
        for (int ci = 0; ci < 16; ++ci) {
            float4 w0 = *reinterpret_cast<const float4*>(wb + ci * 4);              // wx=0
            float4 w1 = *reinterpret_cast<const float4*>(wb + WST + ci * 4);        // wx=1
            float4 w2 = *reinterpret_cast<const float4*>(wb + 2 * WST + ci * 4);    // wx=2
            float v0 = v[0][ci], v1 = v[1][ci], v2 = v[2][ci];
            acc[0][0] += v0 * w1.x; acc[0][1] += v0 * w1.y; acc[0][2] += v0 * w1.z;
            acc[1][0] += v0 * w2.x + v1 * w0.x;
            acc[1][1] += v0 * w2.y + v1 * w0.y;
            acc[1][2] += v0 * w2.z + v1 * w0.z;
            acc[2][0] += v1 * w1.x; acc[2][1] += v1 * w1.y; acc[2][2] += v1 * w1.z;
            acc[3][0] += v1 * w2.x + v2 * w0.x;
            acc[3][1] += v1 * w2.y + v2 * w0.y;
            acc[3][2] += v1 * w2.z + v2 * w0.z;
        }
    }
    int row = (z * SO + y) * SO + x0;
    float4 mm = *reinterpret_cast<const float4*>(m0 + (size_t)b * SO3 + row);
    float mv[4] = {mm.x, mm.y, mm.z, mm.w};
    const float w0o = ow[0], w1o = ow[1], w2o = ow[2], bo = ob[0];
    float yv[3][4], p1[4];
    #pragma unroll
    for (int o = 0; o < 4; ++o) {
        float y0 = sigmoidf_(acc[o][0]) * mv[o];
        float y1 = sigmoidf_(acc[o][1]) * mv[o];
        float y2 = sigmoidf_(acc[o][2]) * mv[o];
        yv[0][o] = y0; yv[1][o] = y1; yv[2][o] = y2;
        p1[o] = sigmoidf_(y0 * w0o + y1 * w1o + y2 * w2o + bo) * mv[o];
    }
    float* ob0 = out + (size_t)b * 3 * SO3 + row;
    #pragma unroll
    for (int c = 0; c < 3; ++c)
        *reinterpret_cast<float4*>(ob0 + (size_t)c * SO3) =
            make_float4(yv[c][0], yv[c][1], yv[c][2], yv[c][3]);
    *reinterpret_cast<float4*>(p1out + (size_t)b * SO3 + row) =
        make_float4(p1[0], p1[1], p1[2], p1[3]);
}

// ============ BN apply (inline finalize) + ReLU + mask (+occ, +skip), CL ======
template<int C, bool OCC, bool ADD>
__global__ __launch_bounds__(256)
void k_bnCL(float* __restrict__ x, const float* __restrict__ m,
            const float* __restrict__ stats, const float* __restrict__ cnt,
            const float* __restrict__ g, const float* __restrict__ be,
            const float* __restrict__ skip, const float* __restrict__ ow,
            const float* __restrict__ ob, float* __restrict__ oo, int totq) {
    constexpr int CQ = C / 4;
    int i = blockIdx.x * 256 + threadIdx.x;
    if (i >= totq) return;
    int vox = i / CQ, cq = i - vox * CQ;
    int c0 = 4 * cq;
    float cn = *cnt;
    float4 s1 = *reinterpret_cast<const float4*>(stats + c0);
    float4 s2 = *reinterpret_cast<const float4*>(stats + 128 + c0);
    float sc[4], sh[4];
    {
        float mean0 = s1.x / cn, mean1 = s1.y / cn, mean2 = s1.z / cn, mean3 = s1.w / cn;
        float v0 = s2.x / cn - mean0 * mean0, v1 = s2.y / cn - mean1 * mean1;
        float v2 = s2.z / cn - mean2 * mean2, v3 = s2.w / cn - mean3 * mean3;
        sc[0] = g[c0] * rsqrtf(v0 + 1e-5f);   sh[0] = be[c0] - mean0 * sc[0];
        sc[1] = g[c0+1] * rsqrtf(v1 + 1e-5f); sh[1] = be[c0+1] - mean1 * sc[1];
        sc[2] = g[c0+2] * rsqrtf(v2 + 1e-5f); sh[2] = be[c0+2] - mean2 * sc[2];
        sc[3] = g[c0+3] * rsqrtf(v3 + 1e-5f); sh[3] = be[c0+3] - mean3 * sc[3];
    }
    float mm = m[vox];
    float4 xv = *reinterpret_cast<const float4*>(x + (size_t)i * 4);
    float y[4];
    y[0] = fmaxf(xv.x * sc[0] + sh[0], 0.f) * mm;
    y[1] = fmaxf(xv.y * sc[1] + sh[1], 0.f) * mm;
    y[2] = fmaxf(xv.z * sc[2] + sh[2], 0.f) * mm;
    y[3] = fmaxf(xv.w * sc[3] + sh[3], 0.f) * mm;
    if constexpr (OCC) {
        float po = y[0] * ow[c0] + y[1] * ow[c0+1] + y[2] * ow[c0+2] + y[3] * ow[c0+3];
        #pragma unroll
        for (int off = 1; off < CQ; off <<= 1) po += __shfl_xor(po, off);
        if (cq == 0) oo[vox] = sigmoidf_(po + ob[0]) * mm;
    }
    if constexpr (ADD) {
        float4 sk = *reinterpret_cast<const float4*>(skip + (size_t)i * 4);
        y[0] += sk.x; y[1] += sk.y; y[2] += sk.z; y[3] += sk.w;
    }
    *reinterpret_cast<float4*>(x + (size_t)i * 4) = make_float4(y[0], y[1], y[2], y[3]);
}

// ---------------- launch ----------------
extern "C" void kernel_launch(void* const* d_in, const int* in_sizes, int n_in,
                              void* d_out, int out_size, void* d_ws, size_t ws_size,
                              hipStream_t stream) {
    (void)in_sizes; (void)n_in; (void)out_size; (void)ws_size;
    const float* feats = (const float*)d_in[0];
    const void*  mraw  = d_in[1];
    const float* W1 = (const float*)d_in[2];
    const float* g1 = (const float*)d_in[3];  const float* b1 = (const float*)d_in[4];
    const float* W2 = (const float*)d_in[5];
    const float* g2 = (const float*)d_in[6];  const float* b2 = (const float*)d_in[7];
    const float* W3 = (const float*)d_in[8];
    const float* g3 = (const float*)d_in[9];  const float* b3 = (const float*)d_in[10];
    const float* W4 = (const float*)d_in[11];
    const float* g4 = (const float*)d_in[12]; const float* b4 = (const float*)d_in[13];
    const float* Wt4 = (const float*)d_in[14];
    const float* gd4 = (const float*)d_in[15]; const float* bd4 = (const float*)d_in[16];
    const float* wo4 = (const float*)d_in[17]; const float* bo4 = (const float*)d_in[18];
    const float* Wt3 = (const float*)d_in[19];
    const float* gd3 = (const float*)d_in[20]; const float* bd3 = (const float*)d_in[21];
    const float* wo3 = (const float*)d_in[22]; const float* bo3 = (const float*)d_in[23];
    const float* Wt2 = (const float*)d_in[24];
    const float* gd2 = (const float*)d_in[25]; const float* bd2 = (const float*)d_in[26];
    const float* wo2 = (const float*)d_in[27]; const float* bo2 = (const float*)d_in[28];
    const float* Wt1 = (const float*)d_in[29];
    const float* wo1 = (const float*)d_in[30]; const float* bo1 = (const float*)d_in[31];

    float* out = (float*)d_out;

    const int NB = 2;
    const int V0 = 96 * 96 * 96;
    const int V1 = 48 * 48 * 48;
    const int V2 = 24 * 24 * 24;
    const int V3 = 12 * 12 * 12;
    const int V4 = 6 * 6 * 6;

    const size_t OFF_P4 = (size_t)NB * 3 * V0;
    const size_t OFF_P3 = OFF_P4 + (size_t)NB * V3;
    const size_t OFF_P2 = OFF_P3 + (size_t)NB * V2;
    const size_t OFF_P1 = OFF_P2 + (size_t)NB * V1;

    float* ws = (float*)d_ws;
    size_t o = 0;
    auto alloc = [&](size_t n) { float* p = ws + o; o += ((n + 63) / 64) * 64; return p; };
    u32*   flag  = (u32*)alloc(64);
    float* cnt   = alloc(64);
    float* stats = alloc(8 * 512);
    float* m0f   = alloc((size_t)NB * V0);
    float* m1f   = alloc((size_t)NB * V1);
    float* m2f   = alloc((size_t)NB * V2);
    float* m3f   = alloc((size_t)NB * V3);
    float* m4f   = alloc((size_t)NB * V4);
    float* e0    = alloc((size_t)NB * V1 * 16);   // channels-last
    float* e1    = alloc((size_t)NB * V2 * 32);
    float* e2    = alloc((size_t)NB * V3 * 64);
    float* e3    = alloc((size_t)NB * V4 * 128);
    float* d3    = alloc((size_t)NB * V3 * 64);
    float* d2    = alloc((size_t)NB * V2 * 32);
    float* d1    = alloc((size_t)NB * V1 * 16);
    (void)alloc(1024);   // guard

    const int T = 256;

    hipMemsetAsync(flag, 0, (64 + 64 + 8 * 512) * sizeof(float), stream);

    // masks
    k_detect<<<256, T, 0, stream>>>((const u32*)mraw, (NB * V0) / 4, flag);
    k_expand<<<CDIV(NB * V0, T), T, 0, stream>>>(mraw, flag, m0f, NB * V0);
    k_pool<<<CDIV(NB * V1, T), T, 0, stream>>>(m0f, m1f, &cnt[0], 96, NB * V1);
    k_pool<<<CDIV(NB * V2, T), T, 0, stream>>>(m1f, m2f, &cnt[1], 48, NB * V2);
    k_pool<<<CDIV(NB * V3, T), T, 0, stream>>>(m2f, m3f, &cnt[2], 24, NB * V3);
    k_pool<<<CDIV(NB * V4, T), T, 0, stream>>>(m3f, m4f, &cnt[3], 12, NB * V4);

    // ---- encoder ----
    k_conv1<<<864, T, 0, stream>>>(feats, m0f, W1, e0, m1f, stats + 0 * 512);
    k_bnCL<16, false, false><<<3456, T, 0, stream>>>(
        e0, m1f, stats + 0 * 512, &cnt[0], g1, b1, nullptr, nullptr, nullptr, nullptr, NB * V1 * 4);

    k_convCL<16, 32, 8, 48, 24, true><<<dim3(108, 4), T, 0, stream>>>(
        e0, W2, e1, m2f, stats + 1 * 512);
    k_bnCL<32, false, false><<<864, T, 0, stream>>>(
        e1, m2f, stats + 1 * 512, &cnt[1], g2, b2, nullptr, nullptr, nullptr, nullptr, NB * V2 * 8);

    k_convCL<32, 64, 4, 24, 12, true><<<dim3(14, 16), T, 0, stream>>>(
        e1, W3, e2, m3f, stats + 2 * 512);
    k_bnCL<64, false, false><<<216, T, 0, stream>>>(
        e2, m3f, stats + 2 * 512, &cnt[2], g3, b3, nullptr, nullptr, nullptr, nullptr, NB * V3 * 16);

    // conv4: direct per-(vox,co), 55296 threads = 216 blocks
    k_convD<64, 128, 12, 6><<<216, T, 0, stream>>>(e2, W4, e3, m4f, stats + 3 * 512);
    k_bnCL<128, false, false><<<54, T, 0, stream>>>(
        e3, m4f, stats + 3 * 512, &cnt[3], g4, b4, nullptr, nullptr, nullptr, nullptr, NB * V4 * 32);

    // ---- decoder 4 -> 3 ---- direct per-(vox,co), 221184 threads = 864 blocks
    k_deconvD<128, 64, 6><<<864, T, 0, stream>>>(e3, Wt4, m3f, d3, stats + 4 * 512);
    k_bnCL<64, true, true><<<216, T, 0, stream>>>(
        d3, m3f, stats + 4 * 512, &cnt[2], gd4, bd4, e2, wo4, bo4, out + OFF_P4, NB * V3 * 16);

    // ---- decoder 3 -> 2 ---- SP_T=2, CO_T=4 x8 groups (NTH=13824, dim3(54,8))
    k_deconvA<64, 32, 4, 2, 12, true><<<dim3(54, 8), T, 0, stream>>>(
        d3, Wt3, m2f, d2, stats + 5 * 512);
    k_bnCL<32, true, true><<<864, T, 0, stream>>>(
        d2, m2f, stats + 5 * 512, &cnt[1], gd3, bd3, e1, wo3, bo3, out + OFF_P3, NB * V2 * 8);

    // ---- decoder 2 -> 1 ---- SP_T=2, CO_T=8 x2 groups (NTH=110592, dim3(432,2))
    k_deconvA<32, 16, 8, 2, 24, true><<<dim3(432, 2), T, 0, stream>>>(
        d2, Wt2, m1f, d1, stats + 6 * 512);
    k_bnCL<16, true, true><<<3456, T, 0, stream>>>(
        d1, m1f, stats + 6 * 512, &cnt[0], gd2, bd2, e0, wo2, bo2, out + OFF_P2, NB * V1 * 4);

    // ---- final level 1 -> 0: gather X4 parity-uniform d0 + p1 fused ----
    k_deconv_final<<<1728, T, 0, stream>>>(d1, Wt1, m0f, out, wo1, bo1, out + OFF_P1);
}

// Round 22
// 378.781 us; speedup vs baseline: 1.0365x; 1.0365x over previous
//
#include <hip/hip_runtime.h>
#include <math.h>

#define CDIV(a,b) (((a)+(b)-1)/(b))
typedef unsigned int u32;

__device__ __forceinline__ float sigmoidf_(float x) { return 1.f / (1.f + __expf(-x)); }

template<int N>
__device__ __forceinline__ void ldsv(float* d, const float* s) {
    #pragma unroll
    for (int q = 0; q < N / 4; ++q) {
        float4 w4 = *reinterpret_cast<const float4*>(s + q * 4);
        d[q*4] = w4.x; d[q*4+1] = w4.y; d[q*4+2] = w4.z; d[q*4+3] = w4.w;
    }
}

// ---------------- mask dtype detection ----------------
__global__ void k_detect(const u32* __restrict__ w, int n, u32* __restrict__ flag) {
    u32 local = 0;
    for (int i = blockIdx.x * blockDim.x + threadIdx.x; i < n; i += gridDim.x * blockDim.x) {
        u32 v = w[i];
        if (v == 0x3F800000u) local |= 2u;
        else if (v > 1u)      local |= 1u;
    }
    if (local) atomicOr(flag, local);
}

__global__ void k_expand(const void* __restrict__ mraw, const u32* __restrict__ flag,
                         float* __restrict__ m, int n) {
    int i = blockIdx.x * blockDim.x + threadIdx.x;
    if (i >= n) return;
    u32 f = *flag;
    float v;
    if (f & 2u)      v = ((const float*)mraw)[i];
    else if (f & 1u) v = ((const unsigned char*)mraw)[i] ? 1.f : 0.f;
    else             v = ((const int*)mraw)[i] ? 1.f : 0.f;
    m[i] = v;
}

// ---------------- mask max-pool 2x2x2 + count ----------------
__global__ void k_pool(const float* __restrict__ mi, float* __restrict__ mo,
                       float* __restrict__ cnt, int Si, int n) {
    int So = Si >> 1;
    int i = blockIdx.x * blockDim.x + threadIdx.x;
    float v = 0.f;
    if (i < n) {
        int x = i % So; int t = i / So;
        int y = t % So; t /= So;
        int z = t % So; int b = t / So;
        const float* p = mi + (size_t)b * Si * Si * Si;
        #pragma unroll
        for (int dz = 0; dz < 2; dz++)
        #pragma unroll
        for (int dy = 0; dy < 2; dy++)
        #pragma unroll
        for (int dx = 0; dx < 2; dx++) {
            float q = p[((size_t)(2 * z + dz) * Si + (2 * y + dy)) * Si + (2 * x + dx)];
            v = fmaxf(v, q);
        }
        mo[i] = v;
    }
    __shared__ float red[256];
    red[threadIdx.x] = v; __syncthreads();
    for (int s = 128; s > 0; s >>= 1) {
        if (threadIdx.x < s) red[threadIdx.x] += red[threadIdx.x + s];
        __syncthreads();
    }
    if (threadIdx.x == 0) atomicAdd(cnt, red[0]);
}

// ============ conv1: NCDHW feats(3ch)+mask -> CL e0, 1 voxel/thread ===========
__global__ __launch_bounds__(256)
void k_conv1(const float* __restrict__ feats, const float* __restrict__ m0,
             const float* __restrict__ W, float* __restrict__ out,
             const float* __restrict__ m1, float* __restrict__ stats) {
    constexpr int SIN = 96;
    constexpr int V0 = SIN * SIN * SIN, V1 = 48 * 48 * 48;
    __shared__ __align__(16) float wlds[27 * 3 * 16];
    __shared__ float sred[4][32];
    for (int idx = threadIdx.x; idx < 27 * 3 * 16; idx += 256) wlds[idx] = W[idx];
    __syncthreads();
    int chunk = blockIdx.x * 256 + threadIdx.x;   // exact: 864*256 = 2*V1
    int b = chunk / V1; int s = chunk - b * V1;
    int x = s % 48, y = (s / 48) % 48, z = s / 2304;
    float acc[16];
    #pragma unroll
    for (int co = 0; co < 16; ++co) acc[co] = 0.f;
    const float* bi = feats + (size_t)b * 3 * V0;
    const float* bm = m0 + (size_t)b * V0;
    #pragma unroll
    for (int kz = 0; kz < 3; ++kz) {
        int iz = 2 * z - 1 + kz; if (iz < 0) continue;
        #pragma unroll
        for (int ky = 0; ky < 3; ++ky) {
            int iy = 2 * y - 1 + ky; if (iy < 0) continue;
            #pragma unroll
            for (int kx = 0; kx < 3; ++kx) {
                int ix = 2 * x - 1 + kx; if (ix < 0) continue;
                int off = (iz * SIN + iy) * SIN + ix;
                float mv = bm[off];
                if (mv != 0.f) {
                    float f0 = bi[off], f1 = bi[V0 + off], f2 = bi[2 * V0 + off];
                    const float* wp = &wlds[((kz * 3 + ky) * 3 + kx) * 48];
                    #pragma unroll
                    for (int co = 0; co < 16; ++co)
                        acc[co] += f0 * wp[co] + f1 * wp[16 + co] + f2 * wp[32 + co];
                }
            }
        }
    }
    float mm = m1[chunk];
    #pragma unroll
    for (int co = 0; co < 16; ++co) acc[co] *= mm;
    float* op = out + (size_t)chunk * 16;
    #pragma unroll
    for (int q = 0; q < 4; ++q)
        *reinterpret_cast<float4*>(op + q * 4) =
            make_float4(acc[q*4], acc[q*4+1], acc[q*4+2], acc[q*4+3]);
    float s1[16], s2[16];
    #pragma unroll
    for (int co = 0; co < 16; ++co) { s1[co] = acc[co]; s2[co] = acc[co] * acc[co]; }
    #pragma unroll
    for (int co = 0; co < 16; ++co)
        for (int off = 1; off < 64; off <<= 1) {
            s1[co] += __shfl_xor(s1[co], off);
            s2[co] += __shfl_xor(s2[co], off);
        }
    int lane = threadIdx.x & 63, wid = threadIdx.x >> 6;
    if (lane == 0) {
        #pragma unroll
        for (int co = 0; co < 16; ++co) { sred[wid][co] = s1[co]; sred[wid][16 + co] = s2[co]; }
    }
    __syncthreads();
    if (threadIdx.x < 32) {
        int t = threadIdx.x;
        float v = sred[0][t] + sred[1][t] + sred[2][t] + sred[3][t];
        int addr = (t < 16) ? t : (128 + t - 16);
        atomicAdd(&stats[addr], v);
    }
}

// ============ channels-last strided conv 3x3x3 s2 p1, gated output ============
template<int CI, int CO, int CO_T, int SIN, int SOUT, bool STATS>
__global__ __launch_bounds__(256)
void k_convCL(const float* __restrict__ in, const float* __restrict__ W,
              float* __restrict__ out, const float* __restrict__ mout,
              float* __restrict__ stats) {
    constexpr int SIN3 = SIN * SIN * SIN, SOUT3 = SOUT * SOUT * SOUT;
    constexpr int NW = 27 * CI * CO_T;
    __shared__ __align__(16) float wlds[NW];
    __shared__ float sred[STATS ? 4 : 1][2 * CO_T];
    const int cobase = blockIdx.y * CO_T;
    for (int idx = threadIdx.x; idx < NW; idx += 256) {
        int t = idx / (CI * CO_T);
        int rem = idx - t * CI * CO_T;
        int ci = rem / CO_T, co = rem - ci * CO_T;
        wlds[idx] = W[(size_t)(t * CI + ci) * CO + cobase + co];
    }
    __syncthreads();
    int chunk = blockIdx.x * 256 + threadIdx.x;
    bool active = chunk < 2 * SOUT3;
    if (!STATS && !active) return;
    float acc[CO_T];
    #pragma unroll
    for (int co = 0; co < CO_T; ++co) acc[co] = 0.f;
    if (active) {
        int b = chunk / SOUT3, s = chunk - b * SOUT3;
        int x = s % SOUT, y = (s / SOUT) % SOUT, z = s / (SOUT * SOUT);
        const float* bi = in + (size_t)b * SIN3 * CI;
        #pragma unroll
        for (int kz = 0; kz < 3; ++kz) {
            int iz = 2 * z - 1 + kz; if (iz < 0 || iz >= SIN) continue;
            #pragma unroll
            for (int ky = 0; ky < 3; ++ky) {
                int iy = 2 * y - 1 + ky; if (iy < 0 || iy >= SIN) continue;
                #pragma unroll
                for (int kx = 0; kx < 3; ++kx) {
                    int ix = 2 * x - 1 + kx; if (ix < 0 || ix >= SIN) continue;
                    const float* p = bi + (size_t)((iz * SIN + iy) * SIN + ix) * CI;
                    const float* wp = &wlds[((kz * 3 + ky) * 3 + kx) * CI * CO_T];
                    #pragma unroll
                    for (int cq = 0; cq < CI / 4; ++cq) {
                        float4 v = *reinterpret_cast<const float4*>(p + cq * 4);
                        const float* wq = wp + cq * 4 * CO_T;
                        float vv[4] = {v.x, v.y, v.z, v.w};
                        #pragma unroll
                        for (int jj = 0; jj < 4; ++jj) {
                            float wv[CO_T];
                            ldsv<CO_T>(wv, wq + jj * CO_T);
                            #pragma unroll
                            for (int co = 0; co < CO_T; ++co)
                                acc[co] += vv[jj] * wv[co];
                        }
                    }
                }
            }
        }
        float mm = mout[chunk];
        #pragma unroll
        for (int co = 0; co < CO_T; ++co) acc[co] *= mm;
        float* op = out + (size_t)chunk * CO + cobase;
        #pragma unroll
        for (int q = 0; q < CO_T / 4; ++q)
            *reinterpret_cast<float4*>(op + q * 4) =
                make_float4(acc[q*4], acc[q*4+1], acc[q*4+2], acc[q*4+3]);
    }
    if constexpr (STATS) {
        float s1[CO_T], s2[CO_T];
        #pragma unroll
        for (int co = 0; co < CO_T; ++co) { s1[co] = acc[co]; s2[co] = acc[co] * acc[co]; }
        #pragma unroll
        for (int co = 0; co < CO_T; ++co)
            for (int off = 1; off < 64; off <<= 1) {
                s1[co] += __shfl_xor(s1[co], off);
                s2[co] += __shfl_xor(s2[co], off);
            }
        int lane = threadIdx.x & 63, wid = threadIdx.x >> 6;
        if (lane == 0) {
            #pragma unroll
            for (int co = 0; co < CO_T; ++co) { sred[wid][co] = s1[co]; sred[wid][CO_T + co] = s2[co]; }
        }
        __syncthreads();
        if (threadIdx.x < 2 * CO_T) {
            int t = threadIdx.x;
            float v = sred[0][t] + sred[1][t] + sred[2][t] + sred[3][t];
            int addr = (t < CO_T) ? (cobase + t) : (128 + cobase + t - CO_T);
            atomicAdd(&stats[addr], v);
        }
    }
}

// ============ DIRECT strided conv s2 p1, thread=(vox,co), no weight LDS =======
template<int CI, int CO, int SIN, int SOUT>
__global__ __launch_bounds__(256)
void k_convD(const float* __restrict__ in, const float* __restrict__ W,
             float* __restrict__ out, const float* __restrict__ mout,
             float* __restrict__ stats) {
    constexpr int SIN3 = SIN * SIN * SIN, SOUT3 = SOUT * SOUT * SOUT;
    int idx = blockIdx.x * 256 + threadIdx.x;
    int co = idx & (CO - 1);
    int vo = idx / CO;
    int b = vo / SOUT3; int s = vo - b * SOUT3;
    int x = s % SOUT, y = (s / SOUT) % SOUT, z = s / (SOUT * SOUT);
    const float* bi = in + (size_t)b * SIN3 * CI;
    float acc = 0.f;
    #pragma unroll 1
    for (int kz = 0; kz < 3; ++kz) {
        int iz = 2 * z - 1 + kz; if (iz < 0 || iz >= SIN) continue;
        #pragma unroll 1
        for (int ky = 0; ky < 3; ++ky) {
            int iy = 2 * y - 1 + ky; if (iy < 0 || iy >= SIN) continue;
            #pragma unroll 1
            for (int kx = 0; kx < 3; ++kx) {
                int ix = 2 * x - 1 + kx; if (ix < 0 || ix >= SIN) continue;
                const float* p = bi + (size_t)((iz * SIN + iy) * SIN + ix) * CI;
                const float* wr = W + (size_t)((kz * 3 + ky) * 3 + kx) * CI * CO + co;
                #pragma unroll 4
                for (int cq = 0; cq < CI / 4; ++cq) {
                    float4 v = *reinterpret_cast<const float4*>(p + 4 * cq);
                    acc += v.x * wr[(size_t)(4 * cq) * CO] + v.y * wr[(size_t)(4 * cq + 1) * CO]
                         + v.z * wr[(size_t)(4 * cq + 2) * CO] + v.w * wr[(size_t)(4 * cq + 3) * CO];
                }
            }
        }
    }
    float gacc = acc * mout[vo];
    out[(size_t)vo * CO + co] = gacc;
    __shared__ float sm1[256], sm2[256];
    int tid = threadIdx.x;
    sm1[tid] = gacc; sm2[tid] = gacc * gacc;
    __syncthreads();
    for (int st = 128; st >= CO; st >>= 1) {
        if (tid < st) { sm1[tid] += sm1[tid + st]; sm2[tid] += sm2[tid + st]; }
        __syncthreads();
    }
    if (tid < CO) {
        atomicAdd(&stats[tid], sm1[tid]);
        atomicAdd(&stats[128 + tid], sm2[tid]);
    }
}

// ============ DIRECT gather deconv s2, thread=(vox,co), no weight LDS =========
template<int CI, int CO, int SIN>
__global__ __launch_bounds__(256)
void k_deconvD(const float* __restrict__ in, const float* __restrict__ W,
               const float* __restrict__ mout, float* __restrict__ out,
               float* __restrict__ stats) {
    constexpr int SOUT = 2 * SIN;
    constexpr int SIN3 = SIN * SIN * SIN, SOUT3 = SOUT * SOUT * SOUT;
    int idx = blockIdx.x * 256 + threadIdx.x;
    int co = idx & (CO - 1);
    int vo = idx / CO;
    int b = vo / SOUT3; int s = vo - b * SOUT3;
    int x = s % SOUT, y = (s / SOUT) % SOUT, z = s / (SOUT * SOUT);
    int z0 = z >> 1, y0 = y >> 1, x0 = x >> 1;
    int nz = ((z & 1) && (z0 + 1 < SIN)) ? 2 : 1;
    int ny = ((y & 1) && (y0 + 1 < SIN)) ? 2 : 1;
    int nx = ((x & 1) && (x0 + 1 < SIN)) ? 2 : 1;
    int wz0 = (z & 1) ? 2 : 1, wy0 = (y & 1) ? 2 : 1, wx0 = (x & 1) ? 2 : 1;
    const float* bi = in + (size_t)b * SIN3 * CI;
    float acc = 0.f;
    #pragma unroll 1
    for (int tz = 0; tz < nz; ++tz) {
        int iz = z0 + tz, wz = tz ? 0 : wz0;
        #pragma unroll 1
        for (int ty = 0; ty < ny; ++ty) {
            int iy = y0 + ty, wy = ty ? 0 : wy0;
            #pragma unroll 1
            for (int tx = 0; tx < nx; ++tx) {
                int ix = x0 + tx, wx = tx ? 0 : wx0;
                const float* p = bi + (size_t)((iz * SIN + iy) * SIN + ix) * CI;
                const float* wr = W + (size_t)((wz * 3 + wy) * 3 + wx) * CI * CO + co;
                #pragma unroll 4
                for (int cq = 0; cq < CI / 4; ++cq) {
                    float4 v = *reinterpret_cast<const float4*>(p + 4 * cq);
                    acc += v.x * wr[(size_t)(4 * cq) * CO] + v.y * wr[(size_t)(4 * cq + 1) * CO]
                         + v.z * wr[(size_t)(4 * cq + 2) * CO] + v.w * wr[(size_t)(4 * cq + 3) * CO];
                }
            }
        }
    }
    float gacc = acc * mout[vo];
    out[(size_t)vo * CO + co] = gacc;
    __shared__ float sm1[256], sm2[256];
    int tid = threadIdx.x;
    sm1[tid] = gacc; sm2[tid] = gacc * gacc;
    __syncthreads();
    for (int st = 128; st >= CO; st >>= 1) {
        if (tid < st) { sm1[tid] += sm1[tid + st]; sm2[tid] += sm2[tid + st]; }
        __syncthreads();
    }
    if (tid < CO) {
        atomicAdd(&stats[tid], sm1[tid]);
        atomicAdd(&stats[128 + tid], sm2[tid]);
    }
}

// ============ amortized GATHER deconv s2, CL: SP_T same-parity x per thread ====
template<int CI, int CO, int CO_T, int SP_T, int SIN, bool STATS>
__global__ __launch_bounds__(256)
void k_deconvA(const float* __restrict__ in, const float* __restrict__ W,
               const float* __restrict__ mout, float* __restrict__ out,
               float* __restrict__ stats) {
    constexpr int SOUT = 2 * SIN;
    constexpr int SIN3 = SIN * SIN * SIN, SOUT3 = SOUT * SOUT * SOUT;
    constexpr int GX = SIN / SP_T;
    constexpr int HALF = 2 * SOUT * SOUT * GX;
    constexpr int NTH = 2 * HALF;
    constexpr int WST = CI * CO_T + 4;   // tap padding: 4 banks shift per tap
    __shared__ __align__(16) float wlds[27 * WST];
    __shared__ float sred[STATS ? 4 : 1][2 * CO_T];
    const int cobase = blockIdx.y * CO_T;
    for (int idx = threadIdx.x; idx < 27 * CI * CO_T; idx += 256) {
        int w = idx / (CI * CO_T);
        int rem = idx - w * (CI * CO_T);
        int ci = rem / CO_T, co = rem - ci * CO_T;
        wlds[w * WST + ci * CO_T + co] = W[(size_t)(w * CI + ci) * CO + cobase + co];
    }
    __syncthreads();
    int chunk = blockIdx.x * 256 + threadIdx.x;
    bool active = chunk < NTH;
    float acc[SP_T][CO_T];
    #pragma unroll
    for (int j = 0; j < SP_T; ++j)
    #pragma unroll
    for (int co = 0; co < CO_T; ++co) acc[j][co] = 0.f;
    int p = 0, g = 0, y = 0, z = 0, b = 0;
    if (active) {
        p = (chunk >= HALF) ? 1 : 0;
        int r = chunk - p * HALF;
        g = r % GX; int q = r / GX;
        y = q % SOUT; q /= SOUT;
        z = q % SOUT; b = q / SOUT;
        int x0 = SP_T * g;
        int z0 = z >> 1, y0 = y >> 1;
        int nz = ((z & 1) && (z0 + 1 < SIN)) ? 2 : 1;
        int ny = ((y & 1) && (y0 + 1 < SIN)) ? 2 : 1;
        int wz0 = (z & 1) ? 2 : 1, wy0 = (y & 1) ? 2 : 1;
        bool lastok = (x0 + SP_T < SIN);
        const float* bi = in + (size_t)b * SIN3 * CI;
        #pragma unroll 1
        for (int tz = 0; tz < nz; ++tz) {
            int iz = z0 + tz, wz = tz ? 0 : wz0;
            #pragma unroll 1
            for (int ty = 0; ty < ny; ++ty) {
                int iy = y0 + ty, wy = ty ? 0 : wy0;
                const float* rp = bi + (size_t)((iz * SIN + iy) * SIN + x0) * CI;
                #pragma unroll 2
                for (int cq = 0; cq < CI / 4; ++cq) {
                    float v[SP_T + 1][4];
                    #pragma unroll
                    for (int t = 0; t < SP_T; ++t) {
                        float4 q4 = *reinterpret_cast<const float4*>(rp + (size_t)t * CI + cq * 4);
                        v[t][0] = q4.x; v[t][1] = q4.y; v[t][2] = q4.z; v[t][3] = q4.w;
                    }
                    if (p) {
                        float4 q4 = make_float4(0.f, 0.f, 0.f, 0.f);
                        if (lastok)
                            q4 = *reinterpret_cast<const float4*>(rp + (size_t)SP_T * CI + cq * 4);
                        v[SP_T][0] = q4.x; v[SP_T][1] = q4.y; v[SP_T][2] = q4.z; v[SP_T][3] = q4.w;
                    }
                    if (p == 0) {
                        const float* wb = &wlds[((wz * 3 + wy) * 3 + 1) * WST + cq * 4 * CO_T];
                        #pragma unroll
                        for (int jj = 0; jj < 4; ++jj) {
                            float wv[CO_T];
                            ldsv<CO_T>(wv, wb + jj * CO_T);
                            #pragma unroll
                            for (int j = 0; j < SP_T; ++j) {
                                float iv = v[j][jj];
                                #pragma unroll
                                for (int co = 0; co < CO_T; ++co) acc[j][co] += iv * wv[co];
                            }
                        }
                    } else {
                        const float* wb2 = &wlds[((wz * 3 + wy) * 3 + 2) * WST + cq * 4 * CO_T];
                        const float* wb0 = &wlds[((wz * 3 + wy) * 3 + 0) * WST + cq * 4 * CO_T];
                        #pragma unroll
                        for (int jj = 0; jj < 4; ++jj) {
                            float wv2[CO_T], wv0[CO_T];
                            ldsv<CO_T>(wv2, wb2 + jj * CO_T);
                            ldsv<CO_T>(wv0, wb0 + jj * CO_T);
                            #pragma unroll
                            for (int j = 0; j < SP_T; ++j) {
                                float ivA = v[j][jj], ivB = v[j + 1][jj];
                                #pragma unroll
                                for (int co = 0; co < CO_T; ++co)
                                    acc[j][co] += ivA * wv2[co] + ivB * wv0[co];
                            }
                        }
                    }
                }
            }
        }
        int sp = b * SOUT3 + (z * SOUT + y) * SOUT;
        int x0o = 2 * SP_T * g + p;
        #pragma unroll
        for (int j = 0; j < SP_T; ++j) {
            int vox = sp + x0o + 2 * j;
            float mm = mout[vox];
            #pragma unroll
            for (int co = 0; co < CO_T; ++co) acc[j][co] *= mm;
            float* op = out + (size_t)vox * CO + cobase;
            #pragma unroll
            for (int q4 = 0; q4 < CO_T / 4; ++q4)
                *reinterpret_cast<float4*>(op + q4 * 4) =
                    make_float4(acc[j][q4*4], acc[j][q4*4+1], acc[j][q4*4+2], acc[j][q4*4+3]);
        }
    }
    if constexpr (STATS) {
        float s1[CO_T], s2[CO_T];
        #pragma unroll
        for (int co = 0; co < CO_T; ++co) {
            float a = 0.f, b2 = 0.f;
            #pragma unroll
            for (int j = 0; j < SP_T; ++j) { a += acc[j][co]; b2 += acc[j][co] * acc[j][co]; }
            s1[co] = a; s2[co] = b2;
        }
        #pragma unroll
        for (int co = 0; co < CO_T; ++co)
            for (int off = 1; off < 64; off <<= 1) {
                s1[co] += __shfl_xor(s1[co], off);
                s2[co] += __shfl_xor(s2[co], off);
            }
        int lane = threadIdx.x & 63, wid = threadIdx.x >> 6;
        if (lane == 0) {
            #pragma unroll
            for (int co = 0; co < CO_T; ++co) { sred[wid][co] = s1[co]; sred[wid][CO_T + co] = s2[co]; }
        }
        __syncthreads();
        if (threadIdx.x < 2 * CO_T) {
            int t = threadIdx.x;
            float v = sred[0][t] + sred[1][t] + sred[2][t] + sred[3][t];
            int addr = (t < CO_T) ? (cobase + t) : (128 + cobase + t - CO_T);
            atomicAdd(&stats[addr], v);
        }
    }
}

// ============ final deconv GATHER X4, parity-uniform waves ====================
__global__ __launch_bounds__(256)
void k_deconv_final(const float* __restrict__ in, const float* __restrict__ W,
                    const float* __restrict__ m0, float* __restrict__ out,
                    const float* __restrict__ ow, const float* __restrict__ ob,
                    float* __restrict__ p1out) {
    constexpr int SI = 48, SO = 96;
    constexpr int SI3 = SI * SI * SI, SO3 = SO * SO * SO;
    constexpr int WST = 68;   // 64 + 4 pad
    __shared__ __align__(16) float wlds[27 * WST];
    for (int idx = threadIdx.x; idx < 27 * 64; idx += 256) {
        int w = idx >> 6; int rem = idx & 63;
        int ci = rem >> 2, co = rem & 3;
        wlds[w * WST + ci * 4 + co] = (co < 3) ? W[(size_t)(w * 16 + ci) * 3 + co] : 0.f;
    }
    __syncthreads();
    int t = blockIdx.x * 256 + threadIdx.x;     // exact 1728*256 = 442368
    int x4 = t % 24; int r = t / 24;
    int yh = r % 48; r /= 48;
    int zh = r % 48; r /= 48;
    int b  = r % 2;  r /= 2;
    int py = r % 2;
    int pz = r / 2;
    int y = 2 * yh + py, z = 2 * zh + pz;
    int x0 = x4 * 4, kxb = x4 * 2;
    int izs[2], wzs[2], nz = 1;
    if (pz) { izs[0] = zh; wzs[0] = 2;
              if (zh + 1 < SI) { izs[1] = zh + 1; wzs[1] = 0; nz = 2; } }
    else    { izs[0] = zh; wzs[0] = 1; }
    int iys[2], wys[2], ny = 1;
    if (py) { iys[0] = yh; wys[0] = 2;
              if (yh + 1 < SI) { iys[1] = yh + 1; wys[1] = 0; ny = 2; } }
    else    { iys[0] = yh; wys[0] = 1; }
    bool has2 = (kxb + 2 < SI);
    float acc[4][3];
    #pragma unroll
    for (int o = 0; o < 4; ++o)
    #pragma unroll
    for (int c = 0; c < 3; ++c) acc[o][c] = 0.f;
    const float* bi = in + (size_t)b * SI3 * 16;
    #pragma unroll 1
    for (int tz = 0; tz < nz; ++tz)
    #pragma unroll 1
    for (int ty = 0; ty < ny; ++ty) {
        const float* vp = bi + ((size_t)(izs[tz] * SI + iys[ty]) * SI + kxb) * 16;
        float v[3][16];
        #pragma unroll
        for (int q = 0; q < 4; ++q) {
            float4 a = *reinterpret_cast<const float4*>(vp + q * 4);
            float4 bq = *reinterpret_cast<const float4*>(vp + 16 + q * 4);
            v[0][q*4] = a.x; v[0][q*4+1] = a.y; v[0][q*4+2] = a.z; v[0][q*4+3] = a.w;
            v[1][q*4] = bq.x; v[1][q*4+1] = bq.y; v[1][q*4+2] = bq.z; v[1][q*4+3] = bq.w;
            float4 cq = has2 ? *reinterpret_cast<const float4*>(vp + 32 + q * 4)
                             : make_float4(0.f, 0.f, 0.f, 0.f);
            v[2][q*4] = cq.x; v[2][q*4+1] = cq.y; v[2][q*4+2] = cq.z; v[2][q*4+3] = cq.w;
        }
        const float* wb = &wlds[((wzs[tz] * 3 + wys[ty]) * 3) * WST];
        #pragma unroll
        for (int ci = 0; ci < 16; ++ci) {
            float4 w0 = *reinterpret_cast<const float4*>(wb + ci * 4);              // wx=0
            float4 w1 = *reinterpret_cast<const float4*>(wb + WST + ci * 4);        // wx=1
            float4 w2 = *reinterpret_cast<const float4*>(wb + 2 * WST + ci * 4);    // wx=2
            float v0 = v[0][ci], v1 = v[1][ci], v2 = v[2][ci];
            acc[0][0] += v0 * w1.x; acc[0][1] += v0 * w1.y; acc[0][2] += v0 * w1.z;
            acc[1][0] += v0 * w2.x + v1 * w0.x;
            acc[1][1] += v0 * w2.y + v1 * w0.y;
            acc[1][2] += v0 * w2.z + v1 * w0.z;
            acc[2][0] += v1 * w1.x; acc[2][1] += v1 * w1.y; acc[2][2] += v1 * w1.z;
            acc[3][0] += v1 * w2.x + v2 * w0.x;
            acc[3][1] += v1 * w2.y + v2 * w0.y;
            acc[3][2] += v1 * w2.z + v2 * w0.z;
        }
    }
    int row = (z * SO + y) * SO + x0;
    float4 mm = *reinterpret_cast<const float4*>(m0 + (size_t)b * SO3 + row);
    float mv[4] = {mm.x, mm.y, mm.z, mm.w};
    const float w0o = ow[0], w1o = ow[1], w2o = ow[2], bo = ob[0];
    float yv[3][4], p1[4];
    #pragma unroll
    for (int o = 0; o < 4; ++o) {
        float y0 = sigmoidf_(acc[o][0]) * mv[o];
        float y1 = sigmoidf_(acc[o][1]) * mv[o];
        float y2 = sigmoidf_(acc[o][2]) * mv[o];
        yv[0][o] = y0; yv[1][o] = y1; yv[2][o] = y2;
        p1[o] = sigmoidf_(y0 * w0o + y1 * w1o + y2 * w2o + bo) * mv[o];
    }
    float* ob0 = out + (size_t)b * 3 * SO3 + row;
    #pragma unroll
    for (int c = 0; c < 3; ++c)
        *reinterpret_cast<float4*>(ob0 + (size_t)c * SO3) =
            make_float4(yv[c][0], yv[c][1], yv[c][2], yv[c][3]);
    *reinterpret_cast<float4*>(p1out + (size_t)b * SO3 + row) =
        make_float4(p1[0], p1[1], p1[2], p1[3]);
}

// ============ BN apply (inline finalize) + ReLU + mask (+occ, +skip), CL ======
template<int C, bool OCC, bool ADD>
__global__ __launch_bounds__(256)
void k_bnCL(float* __restrict__ x, const float* __restrict__ m,
            const float* __restrict__ stats, const float* __restrict__ cnt,
            const float* __restrict__ g, const float* __restrict__ be,
            const float* __restrict__ skip, const float* __restrict__ ow,
            const float* __restrict__ ob, float* __restrict__ oo, int totq) {
    constexpr int CQ = C / 4;
    int i = blockIdx.x * 256 + threadIdx.x;
    if (i >= totq) return;
    int vox = i / CQ, cq = i - vox * CQ;
    int c0 = 4 * cq;
    float cn = *cnt;
    float4 s1 = *reinterpret_cast<const float4*>(stats + c0);
    float4 s2 = *reinterpret_cast<const float4*>(stats + 128 + c0);
    float sc[4], sh[4];
    {
        float mean0 = s1.x / cn, mean1 = s1.y / cn, mean2 = s1.z / cn, mean3 = s1.w / cn;
        float v0 = s2.x / cn - mean0 * mean0, v1 = s2.y / cn - mean1 * mean1;
        float v2 = s2.z / cn - mean2 * mean2, v3 = s2.w / cn - mean3 * mean3;
        sc[0] = g[c0] * rsqrtf(v0 + 1e-5f);   sh[0] = be[c0] - mean0 * sc[0];
        sc[1] = g[c0+1] * rsqrtf(v1 + 1e-5f); sh[1] = be[c0+1] - mean1 * sc[1];
        sc[2] = g[c0+2] * rsqrtf(v2 + 1e-5f); sh[2] = be[c0+2] - mean2 * sc[2];
        sc[3] = g[c0+3] * rsqrtf(v3 + 1e-5f); sh[3] = be[c0+3] - mean3 * sc[3];
    }
    float mm = m[vox];
    float4 xv = *reinterpret_cast<const float4*>(x + (size_t)i * 4);
    float y[4];
    y[0] = fmaxf(xv.x * sc[0] + sh[0], 0.f) * mm;
    y[1] = fmaxf(xv.y * sc[1] + sh[1], 0.f) * mm;
    y[2] = fmaxf(xv.z * sc[2] + sh[2], 0.f) * mm;
    y[3] = fmaxf(xv.w * sc[3] + sh[3], 0.f) * mm;
    if constexpr (OCC) {
        float po = y[0] * ow[c0] + y[1] * ow[c0+1] + y[2] * ow[c0+2] + y[3] * ow[c0+3];
        #pragma unroll
        for (int off = 1; off < CQ; off <<= 1) po += __shfl_xor(po, off);
        if (cq == 0) oo[vox] = sigmoidf_(po + ob[0]) * mm;
    }
    if constexpr (ADD) {
        float4 sk = *reinterpret_cast<const float4*>(skip + (size_t)i * 4);
        y[0] += sk.x; y[1] += sk.y; y[2] += sk.z; y[3] += sk.w;
    }
    *reinterpret_cast<float4*>(x + (size_t)i * 4) = make_float4(y[0], y[1], y[2], y[3]);
}

// ---------------- launch ----------------
extern "C" void kernel_launch(void* const* d_in, const int* in_sizes, int n_in,
                              void* d_out, int out_size, void* d_ws, size_t ws_size,
                              hipStream_t stream) {
    (void)in_sizes; (void)n_in; (void)out_size; (void)ws_size;
    const float* feats = (const float*)d_in[0];
    const void*  mraw  = d_in[1];
    const float* W1 = (const float*)d_in[2];
    const float* g1 = (const float*)d_in[3];  const float* b1 = (const float*)d_in[4];
    const float* W2 = (const float*)d_in[5];
    const float* g2 = (const float*)d_in[6];  const float* b2 = (const float*)d_in[7];
    const float* W3 = (const float*)d_in[8];
    const float* g3 = (const float*)d_in[9];  const float* b3 = (const float*)d_in[10];
    const float* W4 = (const float*)d_in[11];
    const float* g4 = (const float*)d_in[12]; const float* b4 = (const float*)d_in[13];
    const float* Wt4 = (const float*)d_in[14];
    const float* gd4 = (const float*)d_in[15]; const float* bd4 = (const float*)d_in[16];
    const float* wo4 = (const float*)d_in[17]; const float* bo4 = (const float*)d_in[18];
    const float* Wt3 = (const float*)d_in[19];
    const float* gd3 = (const float*)d_in[20]; const float* bd3 = (const float*)d_in[21];
    const float* wo3 = (const float*)d_in[22]; const float* bo3 = (const float*)d_in[23];
    const float* Wt2 = (const float*)d_in[24];
    const float* gd2 = (const float*)d_in[25]; const float* bd2 = (const float*)d_in[26];
    const float* wo2 = (const float*)d_in[27]; const float* bo2 = (const float*)d_in[28];
    const float* Wt1 = (const float*)d_in[29];
    const float* wo1 = (const float*)d_in[30]; const float* bo1 = (const float*)d_in[31];

    float* out = (float*)d_out;

    const int NB = 2;
    const int V0 = 96 * 96 * 96;
    const int V1 = 48 * 48 * 48;
    const int V2 = 24 * 24 * 24;
    const int V3 = 12 * 12 * 12;
    const int V4 = 6 * 6 * 6;

    const size_t OFF_P4 = (size_t)NB * 3 * V0;
    const size_t OFF_P3 = OFF_P4 + (size_t)NB * V3;
    const size_t OFF_P2 = OFF_P3 + (size_t)NB * V2;
    const size_t OFF_P1 = OFF_P2 + (size_t)NB * V1;

    float* ws = (float*)d_ws;
    size_t o = 0;
    auto alloc = [&](size_t n) { float* p = ws + o; o += ((n + 63) / 64) * 64; return p; };
    u32*   flag  = (u32*)alloc(64);
    float* cnt   = alloc(64);
    float* stats = alloc(8 * 512);
    float* m0f   = alloc((size_t)NB * V0);
    float* m1f   = alloc((size_t)NB * V1);
    float* m2f   = alloc((size_t)NB * V2);
    float* m3f   = alloc((size_t)NB * V3);
    float* m4f   = alloc((size_t)NB * V4);
    float* e0    = alloc((size_t)NB * V1 * 16);   // channels-last
    float* e1    = alloc((size_t)NB * V2 * 32);
    float* e2    = alloc((size_t)NB * V3 * 64);
    float* e3    = alloc((size_t)NB * V4 * 128);
    float* d3    = alloc((size_t)NB * V3 * 64);
    float* d2    = alloc((size_t)NB * V2 * 32);
    float* d1    = alloc((size_t)NB * V1 * 16);
    (void)alloc(1024);   // guard

    const int T = 256;

    hipMemsetAsync(flag, 0, (64 + 64 + 8 * 512) * sizeof(float), stream);

    // masks
    k_detect<<<256, T, 0, stream>>>((const u32*)mraw, (NB * V0) / 4, flag);
    k_expand<<<CDIV(NB * V0, T), T, 0, stream>>>(mraw, flag, m0f, NB * V0);
    k_pool<<<CDIV(NB * V1, T), T, 0, stream>>>(m0f, m1f, &cnt[0], 96, NB * V1);
    k_pool<<<CDIV(NB * V2, T), T, 0, stream>>>(m1f, m2f, &cnt[1], 48, NB * V2);
    k_pool<<<CDIV(NB * V3, T), T, 0, stream>>>(m2f, m3f, &cnt[2], 24, NB * V3);
    k_pool<<<CDIV(NB * V4, T), T, 0, stream>>>(m3f, m4f, &cnt[3], 12, NB * V4);

    // ---- encoder ----
    k_conv1<<<864, T, 0, stream>>>(feats, m0f, W1, e0, m1f, stats + 0 * 512);
    k_bnCL<16, false, false><<<3456, T, 0, stream>>>(
        e0, m1f, stats + 0 * 512, &cnt[0], g1, b1, nullptr, nullptr, nullptr, nullptr, NB * V1 * 4);

    k_convCL<16, 32, 8, 48, 24, true><<<dim3(108, 4), T, 0, stream>>>(
        e0, W2, e1, m2f, stats + 1 * 512);
    k_bnCL<32, false, false><<<864, T, 0, stream>>>(
        e1, m2f, stats + 1 * 512, &cnt[1], g2, b2, nullptr, nullptr, nullptr, nullptr, NB * V2 * 8);

    k_convCL<32, 64, 4, 24, 12, true><<<dim3(14, 16), T, 0, stream>>>(
        e1, W3, e2, m3f, stats + 2 * 512);
    k_bnCL<64, false, false><<<216, T, 0, stream>>>(
        e2, m3f, stats + 2 * 512, &cnt[2], g3, b3, nullptr, nullptr, nullptr, nullptr, NB * V3 * 16);

    // conv4: direct per-(vox,co), 55296 threads = 216 blocks
    k_convD<64, 128, 12, 6><<<216, T, 0, stream>>>(e2, W4, e3, m4f, stats + 3 * 512);
    k_bnCL<128, false, false><<<54, T, 0, stream>>>(
        e3, m4f, stats + 3 * 512, &cnt[3], g4, b4, nullptr, nullptr, nullptr, nullptr, NB * V4 * 32);

    // ---- decoder 4 -> 3 ---- direct per-(vox,co), 221184 threads = 864 blocks
    k_deconvD<128, 64, 6><<<864, T, 0, stream>>>(e3, Wt4, m3f, d3, stats + 4 * 512);
    k_bnCL<64, true, true><<<216, T, 0, stream>>>(
        d3, m3f, stats + 4 * 512, &cnt[2], gd4, bd4, e2, wo4, bo4, out + OFF_P4, NB * V3 * 16);

    // ---- decoder 3 -> 2 ---- SP_T=2, CO_T=4 x8 groups (NTH=13824, dim3(54,8))
    k_deconvA<64, 32, 4, 2, 12, true><<<dim3(54, 8), T, 0, stream>>>(
        d3, Wt3, m2f, d2, stats + 5 * 512);
    k_bnCL<32, true, true><<<864, T, 0, stream>>>(
        d2, m2f, stats + 5 * 512, &cnt[1], gd3, bd3, e1, wo3, bo3, out + OFF_P3, NB * V2 * 8);

    // ---- decoder 2 -> 1 ---- SP_T=2, CO_T=8 x2 groups (NTH=110592, dim3(432,2))
    k_deconvA<32, 16, 8, 2, 24, true><<<dim3(432, 2), T, 0, stream>>>(
        d2, Wt2, m1f, d1, stats + 6 * 512);
    k_bnCL<16, true, true><<<3456, T, 0, stream>>>(
        d1, m1f, stats + 6 * 512, &cnt[0], gd2, bd2, e0, wo2, bo2, out + OFF_P2, NB * V1 * 4);

    // ---- final level 1 -> 0: gather X4 parity-uniform d0 + p1 fused ----
    k_deconv_final<<<1728, T, 0, stream>>>(d1, Wt1, m0f, out, wo1, bo1, out + OFF_P1);
}